// Round 11
// baseline (186.346 us; speedup 1.0000x reference)
//
#include <hip/hip_runtime.h>
#include <hip/hip_cooperative_groups.h>

namespace cg = cooperative_groups;

#define N_PTS  20000
#define NG     128                  // grid NG x NG over [-6,6]^2
#define NC     (NG * NG)            // 16384 cells per cloud
#define GMIN   (-6.0f)
#define GINV   (NG / 12.0f)
#define MARGIN 5e-4f                // >> 2e-5 worst-case |P_np - d_true^2|
#define SSTRIDE (N_PTS / 64)        // 312; 63*312 = 19656 < 20000
#define NBLK_STAGE 157              // 40192 threads; co-resident trivially
#define QB79   79                   // fallback

// ---- numpy-exact helpers (proven rounds 2/5/9/10/11/14) ----
__device__ __forceinline__ float np_self_dot(float x, float y, float z) {
    return __fadd_rn(__fadd_rn(__fmul_rn(x, x), __fmul_rn(y, y)),
                     __fmul_rn(z, z));
}
__device__ __forceinline__ unsigned ordmap(float f) {
    unsigned b = __float_as_uint(f);
    return (b & 0x80000000u) ? ~b : (b | 0x80000000u);
}
__device__ __forceinline__ float invord(unsigned h) {
    return __uint_as_float((h & 0x80000000u) ? (h ^ 0x80000000u) : ~h);
}
__device__ __forceinline__ int cellC(float v) {
    int c = (int)((v - GMIN) * GINV);
    return c < 0 ? 0 : (c > NG - 1 ? NG - 1 : c);
}
__device__ __forceinline__ unsigned long long wave_min_u64(unsigned long long k) {
    #pragma unroll
    for (int m = 1; m < 64; m <<= 1) {
        unsigned long long o = __shfl_xor(k, m, 64);
        k = (o < k) ? o : k;
    }
    return k;
}

// Candidate evaluation (bit-identical numerics, key=(ordmap(P)<<32|idx)).
// Uses names qx,qy,qz,sq,key from the enclosing scope.
#define EVAL(r)                                                            \
    {   float sr = np_self_dot((r).x, (r).y, (r).z);                       \
        float zz = __fadd_rn(__fadd_rn(__fmul_rn(qx, (r).x),               \
                                       __fmul_rn(qy, (r).y)),              \
                             __fmul_rn(qz, (r).z));                        \
        float P  = __fsub_rn(__fadd_rn(sq, sr), __fadd_rn(zz, zz));        \
        unsigned long long kk =                                            \
            ((unsigned long long)ordmap(P) << 32) | __float_as_uint((r).w);\
        key = (kk < key) ? kk : key; }

// ---- 3-row flat stream (r23, PROVEN): lanes walk the concatenated
// candidate space of up to 3 y-clipped row intervals [lo_i, lo_i+c_i).
// Row lookup = 2-comparison ternary map. 2-deep software pipeline.
__device__ __forceinline__ void stream3(
    const float4* __restrict__ rs, int lane,
    int lo0, int c0, int lo1, int c1, int lo2, int c2,
    float qx, float qy, float qz, float sq, unsigned long long& key)
{
    int s01 = c0 + c1, tot = s01 + c2;
    int t = lane;
    if (t < tot) {
        int p = t < c0 ? lo0 + t : t < s01 ? lo1 + (t - c0) : lo2 + (t - s01);
        float4 rc = rs[p];
        for (t += 64; t < tot; t += 64) {
            int pn = t < c0 ? lo0 + t : t < s01 ? lo1 + (t - c0)
                                                : lo2 + (t - s01);
            float4 rn = rs[pn];                       // next load in flight
            EVAL(rc)
            rc = rn;
        }
        EVAL(rc)
    }
}

// ---- fused staging (r25): memset+hist+scan+scatter in ONE cooperative
// kernel. Dispatch-count was the dominant non-k_main cost: total-k_main
// gap stayed 64-70us across r0..r23 regardless of staging structure
// (~10us/dispatch x 5). r19's fused-staging blame is reassigned: r20
// proved the flattened scan_box (also present in r19) was broken on its
// own; fused staging itself was never isolated. This version uses the
// OFFICIAL grid.sync() (hipLaunchCooperativeKernel) instead of r19's
// hand-rolled fence barrier, and belt-and-braces agent-scope atomic
// load/store for every value crossing a sync inside the kernel (cursor
// counts, cursor starts, btot). sorted/bstart are read only by k_main,
// a separate dispatch — kernel-boundary visibility (safe r16-r23 path).
// Cell partition: 2*NC = 32768 cells = blocks 0..127 x 256 (1 cell/thread,
// 64 blocks/cloud). Points: 40192 threads >= 40000.
__global__ __launch_bounds__(256) void k_stage(
    const float* __restrict__ preds, const float* __restrict__ gts,
    int* __restrict__ cursor, int* __restrict__ bstart,
    float4* __restrict__ sorted, int* __restrict__ btot)
{
    cg::grid_group grid = cg::this_grid();
    __shared__ int wtot[4];
    int t = blockIdx.x * 256 + threadIdx.x;
    int lane = threadIdx.x & 63, wav = (int)threadIdx.x >> 6;

    // phase 0: zero cursor (replaces the hipMemsetAsync dispatch)
    if (t < 2 * NC)
        __hip_atomic_store(&cursor[t], 0, __ATOMIC_RELAXED,
                           __HIP_MEMORY_SCOPE_AGENT);
    grid.sync();

    // phase 1: histogram (device-scope atomicAdd)
    int cl = 0, i = 0, cell = 0;
    float x = 0.f, y = 0.f, z = 0.f;
    bool valid = t < 2 * N_PTS;
    if (valid) {
        cl = t / N_PTS; i = t - cl * N_PTS;
        const float* src = cl ? gts : preds;
        x = src[i*3+0]; y = src[i*3+1]; z = src[i*3+2];
        cell = cellC(x) * NG + cellC(y);
        atomicAdd(&cursor[cl * NC + cell], 1);
    }
    grid.sync();

    // phase 2a: block-local scan over cells (blocks 0..127, block-uniform)
    bool scanb = t < 2 * NC;
    int texcl = 0, blkexcl = 0;
    if (scanb) {
        int cnt = __hip_atomic_load(&cursor[t], __ATOMIC_RELAXED,
                                    __HIP_MEMORY_SCOPE_AGENT);
        int ps = cnt;                               // inclusive 64-lane scan
        #pragma unroll
        for (int m = 1; m < 64; m <<= 1) {
            int o = __shfl_up(ps, m, 64);
            if (lane >= m) ps += o;
        }
        if (lane == 63) wtot[wav] = ps;
        texcl = ps - cnt;                           // excl within wave
        __syncthreads();                            // block-uniform path
        int bsum = 0;
        #pragma unroll
        for (int wv = 0; wv < 4; ++wv) {
            int v = wtot[wv];
            if (wv < wav) blkexcl += v;             // excl wave prefix
            bsum += v;
        }
        if (threadIdx.x == 0)
            __hip_atomic_store(&btot[blockIdx.x], bsum, __ATOMIC_RELAXED,
                               __HIP_MEMORY_SCOPE_AGENT);
    }
    grid.sync();

    // phase 2b: cross-block prefix (<=64 preceding blocks per cloud)
    if (scanb) {
        int c  = (int)blockIdx.x >> 6;              // cloud
        int b0 = (int)blockIdx.x & 63;              // block within cloud
        int v = (lane < b0)
            ? __hip_atomic_load(&btot[(c << 6) + lane], __ATOMIC_RELAXED,
                                __HIP_MEMORY_SCOPE_AGENT)
            : 0;
        #pragma unroll
        for (int m = 1; m < 64; m <<= 1) v += __shfl_xor(v, m, 64);
        int run = v + blkexcl + texcl;              // excl prefix in cloud
        int ci  = t & (NC - 1);                     // cell within cloud
        bstart[c * (NC + 1) + ci] = run;
        __hip_atomic_store(&cursor[t], run, __ATOMIC_RELAXED,
                           __HIP_MEMORY_SCOPE_AGENT);
        if (ci == NC - 1) bstart[c * (NC + 1) + NC] = N_PTS;  // sentinel
    }
    grid.sync();

    // phase 3: scatter into cell-sorted order (r14 record layout)
    if (valid) {
        int pos = atomicAdd(&cursor[cl * NC + cell], 1);
        sorted[(size_t)cl * N_PTS + pos] = make_float4(x, y, z,
                                                       __int_as_float(i));
    }
}

// ---- main (r23 EXACT, PROVEN 52.5us): y-clipped rows + parallel flat
// loading; 40000 1-wave blocks (dynamic HW scheduling = load balancing —
// r24's static persistent waves regressed 52->63-75us and are reverted).
// seed: ONE lane-scattered bounds load -> 3-row flat stream; phase2 (only
// if W-box escapes seed): ONE bounds load per <=32 rows, triples from
// registers. W-certificate: W^2 = d_seed + MARGIN; any unscanned point has
// P > W^2 > d_final + numerics. Rescans idempotent. samp EVAL guarantees a
// valid bound. Numerics bit-identical to r9-r23: numpy-exact P;
// key=(ordmap(P)<<32|idx); wave-min == numpy first-occurrence argmin.
__global__ __launch_bounds__(64) void k_main(
    const float4* __restrict__ sorted, const int* __restrict__ bstart,
    float* __restrict__ out)
{
    int wid  = blockIdx.x;                                 // 0..39999
    int lane = threadIdx.x;                                // 0..63
    int dir  = wid / N_PTS;
    int qpos = wid - dir * N_PTS;
    int rcl  = 1 - dir;

    const float4* rs = sorted + (size_t)rcl * N_PTS;
    const int*    cs = bstart + rcl * (NC + 1);

    float4 samp = rs[lane * SSTRIDE];                  // independent, early
    float4 qv   = sorted[(size_t)dir * N_PTS + qpos];  // wave-broadcast
    int    origq = __float_as_int(qv.w);
    float qx = qv.x, qy = qv.y, qz = qv.z;
    float sq = np_self_dot(qx, qy, qz);

    unsigned long long key = ~0ULL;
    int l31 = lane & 31;

    // phase 1: seed = 3x3 cell box, y-clipped rows, one bounds load
    int cx = cellC(qx), cy = cellC(qy);
    int sxL = cx > 0 ? cx - 1 : 0, sxR = cx < NG-1 ? cx + 1 : NG-1;
    int syL = cy > 0 ? cy - 1 : 0, syR = cy < NG-1 ? cy + 1 : NG-1;
    int nrs  = sxR - sxL + 1;                          // 2 or 3
    int xrS  = sxL + (l31 < nrs ? l31 : nrs - 1);
    int colS = (lane < 32) ? syL : (syR + 1);          // end = next col start
    int bndS = cs[xrS * NG + colS];                    // ONE scattered load
    int lo0 = __shfl(bndS, 0, 64), hi0 = __shfl(bndS, 32, 64);
    int lo1 = __shfl(bndS, 1, 64), hi1 = __shfl(bndS, 33, 64);
    int lo2 = __shfl(bndS, 2, 64), hi2 = __shfl(bndS, 34, 64);
    int c0 = hi0 - lo0;
    int c1 = nrs > 1 ? hi1 - lo1 : 0;
    int c2 = nrs > 2 ? hi2 - lo2 : 0;
    stream3(rs, lane, lo0, c0, lo1, c1, lo2, c2, qx, qy, qz, sq, key);
    EVAL(samp)                        // guaranteed-valid upper bound

    // phase 2: certified W-box scan (exact cells, rescans idempotent)
    key = wave_min_u64(key);
    float W = sqrtf(invord((unsigned)(key >> 32)) + MARGIN);
    int txL = cellC(qx - W), txR = cellC(qx + W);
    int tyL = cellC(qy - W), tyR = cellC(qy + W);
    if (!(txL >= sxL && txR <= sxR && tyL >= syL && tyR <= syR)) {
        int R = txR - txL + 1;
        for (int g = 0; g < R; g += 32) {
            int rows = R - g; if (rows > 32) rows = 32;
            int xr2  = txL + g + (l31 < rows ? l31 : rows - 1);
            int col2 = (lane < 32) ? tyL : (tyR + 1);
            int b2 = cs[xr2 * NG + col2];              // ONE load / 32 rows
            for (int r0 = 0; r0 < rows; r0 += 3) {     // triples from regs
                int i1 = r0 + 1 < rows ? r0 + 1 : rows - 1;
                int i2 = r0 + 2 < rows ? r0 + 2 : rows - 1;
                int L0 = __shfl(b2, r0, 64), H0 = __shfl(b2, 32 + r0, 64);
                int L1 = __shfl(b2, i1, 64), H1 = __shfl(b2, 32 + i1, 64);
                int L2 = __shfl(b2, i2, 64), H2 = __shfl(b2, 32 + i2, 64);
                int d0 = H0 - L0;
                int d1 = (r0 + 1 < rows) ? H1 - L1 : 0;
                int d2 = (r0 + 2 < rows) ? H2 - L2 : 0;
                stream3(rs, lane, L0, d0, L1, d1, L2, d2,
                        qx, qy, qz, sq, key);
            }
        }
        key = wave_min_u64(key);
    }

    if (lane == 0) {
        out[dir * N_PTS + origq]       = invord((unsigned)(key >> 32));
        out[(2 + dir) * N_PTS + origq] = (float)(unsigned)(key & 0xFFFFFFFFu);
    }
}

// ---- fallback (tiny workspace): brute-force direct kernel (proven r2) ----
__device__ __forceinline__ float np_pair(float sq, float sr,
                                         float qx, float qy, float qz,
                                         float rx, float ry, float rz) {
    float zz = __fadd_rn(__fadd_rn(__fmul_rn(qx, rx), __fmul_rn(qy, ry)),
                         __fmul_rn(qz, rz));
    return __fsub_rn(__fadd_rn(sq, sr), __fadd_rn(zz, zz));
}

__global__ __launch_bounds__(256) void chamfer_direct_kernel(
    const float* __restrict__ preds, const float* __restrict__ gts,
    float* __restrict__ out)
{
    __shared__ float4 spts[256];
    int bid = blockIdx.x;
    int dir = bid / QB79;
    int qb  = bid - dir * QB79;
    int q   = qb * 256 + threadIdx.x;

    const float* qpts = (dir == 0) ? preds : gts;
    const float* rpts = (dir == 0) ? gts   : preds;

    int qc = (q < N_PTS) ? q : (N_PTS - 1);
    float qx = qpts[qc*3+0], qy = qpts[qc*3+1], qz = qpts[qc*3+2];
    float sq = np_self_dot(qx, qy, qz);
    float best = 3.4e38f;
    int   bidx = 0;

    for (int t = 0; t < N_PTS; t += 256) {
        int cnt = min(256, N_PTS - t);
        __syncthreads();
        if ((int)threadIdx.x < cnt) {
            int j = t + threadIdx.x;
            float rx = rpts[j*3+0], ry = rpts[j*3+1], rz = rpts[j*3+2];
            spts[threadIdx.x] = make_float4(rx, ry, rz, np_self_dot(rx, ry, rz));
        }
        __syncthreads();
        for (int k = 0; k < cnt; ++k) {
            float4 r = spts[k];
            float d = np_pair(sq, r.w, qx, qy, qz, r.x, r.y, r.z);
            if (d < best) { best = d; bidx = t + k; }
        }
    }
    if (q < N_PTS) {
        out[dir * N_PTS + q]       = best;
        out[(2 + dir) * N_PTS + q] = (float)bidx;
    }
}

extern "C" void kernel_launch(void* const* d_in, const int* in_sizes, int n_in,
                              void* d_out, int out_size, void* d_ws, size_t ws_size,
                              hipStream_t stream) {
    const float* preds = (const float*)d_in[0];  // [20000, 3]
    const float* gts   = (const float*)d_in[1];  // [1, 20000, 3]
    float* out = (float*)d_out;

    // layout: sorted | bstart | cursor | btot
    char* w = (char*)d_ws;
    size_t sorted_b = (size_t)2 * N_PTS * sizeof(float4);   // 640000
    size_t bstart_b = (size_t)2 * (NC + 1) * sizeof(int);   // 131080
    size_t cursor_b = (size_t)2 * NC * sizeof(int);         // 131072
    size_t btot_b   = 128 * sizeof(int);                    // 512
    size_t need = sorted_b + bstart_b + cursor_b + btot_b;

    if (ws_size >= need) {
        float4* sorted = (float4*)w;
        int* bstart = (int*)(w + sorted_b);
        int* cursor = (int*)(w + sorted_b + bstart_b);
        int* btot   = (int*)(w + sorted_b + bstart_b + cursor_b);

        void* args[6] = { (void*)&preds, (void*)&gts, (void*)&cursor,
                          (void*)&bstart, (void*)&sorted, (void*)&btot };
        hipLaunchCooperativeKernel((void*)k_stage, dim3(NBLK_STAGE),
                                   dim3(256), args, 0, stream);
        k_main<<<2 * N_PTS, 64, 0, stream>>>(sorted, bstart, out);
    } else {
        chamfer_direct_kernel<<<2 * QB79, 256, 0, stream>>>(preds, gts, out);
    }
}

// Round 12
// 123.114 us; speedup vs baseline: 1.5136x; 1.5136x over previous
//
#include <hip/hip_runtime.h>

#define N_PTS  20000
#define NG     128                  // grid NG x NG over [-6,6]^2
#define NC     (NG * NG)            // 16384 cells per cloud
#define GMIN   (-6.0f)
#define GINV   (NG / 12.0f)
#define MARGIN 5e-4f                // >> 2e-5 worst-case |P_np - d_true^2|
#define SSTRIDE (N_PTS / 64)        // 312; 63*312 = 19656 < 20000
#define QB79   79                   // fallback

// ---- numpy-exact helpers (proven rounds 2/5/9/10/11/14) ----
__device__ __forceinline__ float np_self_dot(float x, float y, float z) {
    return __fadd_rn(__fadd_rn(__fmul_rn(x, x), __fmul_rn(y, y)),
                     __fmul_rn(z, z));
}
__device__ __forceinline__ unsigned ordmap(float f) {
    unsigned b = __float_as_uint(f);
    return (b & 0x80000000u) ? ~b : (b | 0x80000000u);
}
__device__ __forceinline__ float invord(unsigned h) {
    return __uint_as_float((h & 0x80000000u) ? (h ^ 0x80000000u) : ~h);
}
__device__ __forceinline__ int cellC(float v) {
    int c = (int)((v - GMIN) * GINV);
    return c < 0 ? 0 : (c > NG - 1 ? NG - 1 : c);
}
__device__ __forceinline__ unsigned long long wave_min_u64(unsigned long long k) {
    #pragma unroll
    for (int m = 1; m < 64; m <<= 1) {
        unsigned long long o = __shfl_xor(k, m, 64);
        k = (o < k) ? o : k;
    }
    return k;
}

// Candidate evaluation (bit-identical numerics, key=(ordmap(P)<<32|idx)).
// Uses names qx,qy,qz,sq,key from the enclosing scope.
#define EVAL(r)                                                            \
    {   float sr = np_self_dot((r).x, (r).y, (r).z);                       \
        float zz = __fadd_rn(__fadd_rn(__fmul_rn(qx, (r).x),               \
                                       __fmul_rn(qy, (r).y)),              \
                             __fmul_rn(qz, (r).z));                        \
        float P  = __fsub_rn(__fadd_rn(sq, sr), __fadd_rn(zz, zz));        \
        unsigned long long kk =                                            \
            ((unsigned long long)ordmap(P) << 32) | __float_as_uint((r).w);\
        key = (kk < key) ? kk : key; }

// ---- 3-row flat stream (r23, PROVEN): lanes walk the concatenated
// candidate space of up to 3 y-clipped row intervals [lo_i, lo_i+c_i).
// Row lookup = 2-comparison ternary map. 2-deep software pipeline.
__device__ __forceinline__ void stream3(
    const float4* __restrict__ rs, int lane,
    int lo0, int c0, int lo1, int c1, int lo2, int c2,
    float qx, float qy, float qz, float sq, unsigned long long& key)
{
    int s01 = c0 + c1, tot = s01 + c2;
    int t = lane;
    if (t < tot) {
        int p = t < c0 ? lo0 + t : t < s01 ? lo1 + (t - c0) : lo2 + (t - s01);
        float4 rc = rs[p];
        for (t += 64; t < tot; t += 64) {
            int pn = t < c0 ? lo0 + t : t < s01 ? lo1 + (t - c0)
                                                : lo2 + (t - s01);
            float4 rn = rs[pn];                       // next load in flight
            EVAL(rc)
            rc = rn;
        }
        EVAL(rc)
    }
}

// ---- build A1 (r16/r18, PROVEN): wide parallel histogram, global atomics ----
__global__ __launch_bounds__(256) void k_hist(
    const float* __restrict__ preds, const float* __restrict__ gts,
    int* __restrict__ cursor)
{
    int t = blockIdx.x * 256 + threadIdx.x;
    if (t >= 2 * N_PTS) return;
    int cl = t / N_PTS, i = t - cl * N_PTS;
    const float* src = cl ? gts : preds;
    int cell = cellC(src[i*3+0]) * NG + cellC(src[i*3+1]);
    atomicAdd(&cursor[cl * NC + cell], 1);
}

// ---- build A2 (r22, PROVEN): scan via shfl wave-scans, 2 barriers ----
__global__ __launch_bounds__(1024) void k_scan(
    int* __restrict__ cursor, int* __restrict__ bstart)
{
    __shared__ int wsum[16];
    __shared__ int wpre[16];
    int cl = blockIdx.x, t = threadIdx.x;
    int wave = t >> 6, lane = t & 63;

    int base = cl * NC + t * 16;                    // 64B-aligned (ws layout)
    const int4* c4 = (const int4*)(cursor + base);
    int4 a = c4[0], b = c4[1], c = c4[2], d = c4[3];
    int v[16] = { a.x, a.y, a.z, a.w, b.x, b.y, b.z, b.w,
                  c.x, c.y, c.z, c.w, d.x, d.y, d.z, d.w };
    int s = 0;
    #pragma unroll
    for (int i = 0; i < 16; ++i) s += v[i];

    int ps = s;                                     // inclusive 64-lane scan
    #pragma unroll
    for (int m = 1; m < 64; m <<= 1) {
        int o = __shfl_up(ps, m, 64);
        if (lane >= m) ps += o;
    }
    if (lane == 63) wsum[wave] = ps;
    __syncthreads();
    if (t < 16) {
        int x = wsum[t];
        int px = x;                                 // inclusive 16-scan
        #pragma unroll
        for (int m = 1; m < 16; m <<= 1) {
            int o = __shfl_up(px, m, 16);
            if ((t & 15) >= m) px += o;
        }
        wpre[t] = px - x;                           // exclusive wave prefix
    }
    __syncthreads();

    int run = wpre[wave] + (ps - s);                // exclusive thread prefix
    #pragma unroll
    for (int i = 0; i < 16; ++i) {
        bstart[cl * (NC + 1) + t * 16 + i] = run;
        cursor[base + i] = run;
        run += v[i];
    }
    if (t == 1023) bstart[cl * (NC + 1) + NC] = run;   // == N_PTS
}

// ---- build B (r15/r18, PROVEN): wide scatter into cell-sorted order ----
__global__ __launch_bounds__(256) void k_scatter(
    const float* __restrict__ preds, const float* __restrict__ gts,
    int* __restrict__ cursor, float4* __restrict__ sorted)
{
    int t = blockIdx.x * 256 + threadIdx.x;
    if (t >= 2 * N_PTS) return;
    int cl = t / N_PTS, i = t - cl * N_PTS;
    const float* src = cl ? gts : preds;
    float x = src[i*3+0], y = src[i*3+1], z = src[i*3+2];
    int cell = cellC(x) * NG + cellC(y);
    int pos = atomicAdd(&cursor[cl * NC + cell], 1);
    sorted[(size_t)cl * N_PTS + pos] = make_float4(x, y, z, __int_as_float(i));
}

// ---- main (r26): r23 per-wave algorithm UNCHANGED; geometry = 4 waves
// per block (256 thr), 10000 blocks. r23/r25 post-mortems: k_main was
// BLOCK-DISPATCH-RATE limited — occ 25% == dispatch_rate(762 blk/us) x
// lifetime(2.7us) exactly, and 40000 blk / 770 blk/us == the measured
// 52.5us. 4 independent waves/block (one query each, no __syncthreads,
// full-64-lane — NOT r16's subgroup sharing; r18 proved 4-wave-block
// correctness) cuts the dispatch floor to ~13us and lets residency reach
// the 32-waves/CU cap. Adjacent queries are cell-sorted => correlated
// cost => mild block-retire tail. Numerics bit-identical to r9-r23:
// numpy-exact P; key=(ordmap(P)<<32|idx); wave-min == numpy
// first-occurrence argmin; samp upper bound (no empty-seed path);
// W-certificate W^2 = d_seed + MARGIN; rescans idempotent.
__global__ __launch_bounds__(256) void k_main(
    const float4* __restrict__ sorted, const int* __restrict__ bstart,
    float* __restrict__ out)
{
    int wid  = blockIdx.x * 4 + ((int)threadIdx.x >> 6);   // 0..39999
    int lane = threadIdx.x & 63;
    int dir  = wid / N_PTS;
    int qpos = wid - dir * N_PTS;
    int rcl  = 1 - dir;

    const float4* rs = sorted + (size_t)rcl * N_PTS;
    const int*    cs = bstart + rcl * (NC + 1);

    float4 samp = rs[lane * SSTRIDE];                  // independent, early
    float4 qv   = sorted[(size_t)dir * N_PTS + qpos];  // wave-broadcast
    int    origq = __float_as_int(qv.w);
    float qx = qv.x, qy = qv.y, qz = qv.z;
    float sq = np_self_dot(qx, qy, qz);

    unsigned long long key = ~0ULL;
    int l31 = lane & 31;

    // phase 1: seed = 3x3 cell box, y-clipped rows, one bounds load
    int cx = cellC(qx), cy = cellC(qy);
    int sxL = cx > 0 ? cx - 1 : 0, sxR = cx < NG-1 ? cx + 1 : NG-1;
    int syL = cy > 0 ? cy - 1 : 0, syR = cy < NG-1 ? cy + 1 : NG-1;
    int nrs  = sxR - sxL + 1;                          // 2 or 3
    int xrS  = sxL + (l31 < nrs ? l31 : nrs - 1);
    int colS = (lane < 32) ? syL : (syR + 1);          // end = next col start
    int bndS = cs[xrS * NG + colS];                    // ONE scattered load
    int lo0 = __shfl(bndS, 0, 64), hi0 = __shfl(bndS, 32, 64);
    int lo1 = __shfl(bndS, 1, 64), hi1 = __shfl(bndS, 33, 64);
    int lo2 = __shfl(bndS, 2, 64), hi2 = __shfl(bndS, 34, 64);
    int c0 = hi0 - lo0;
    int c1 = nrs > 1 ? hi1 - lo1 : 0;
    int c2 = nrs > 2 ? hi2 - lo2 : 0;
    stream3(rs, lane, lo0, c0, lo1, c1, lo2, c2, qx, qy, qz, sq, key);
    EVAL(samp)                        // guaranteed-valid upper bound

    // phase 2: certified W-box scan (exact cells, rescans idempotent)
    key = wave_min_u64(key);
    float W = sqrtf(invord((unsigned)(key >> 32)) + MARGIN);
    int txL = cellC(qx - W), txR = cellC(qx + W);
    int tyL = cellC(qy - W), tyR = cellC(qy + W);
    if (!(txL >= sxL && txR <= sxR && tyL >= syL && tyR <= syR)) {
        int R = txR - txL + 1;
        for (int g = 0; g < R; g += 32) {
            int rows = R - g; if (rows > 32) rows = 32;
            int xr2  = txL + g + (l31 < rows ? l31 : rows - 1);
            int col2 = (lane < 32) ? tyL : (tyR + 1);
            int b2 = cs[xr2 * NG + col2];              // ONE load / 32 rows
            for (int r0 = 0; r0 < rows; r0 += 3) {     // triples from regs
                int i1 = r0 + 1 < rows ? r0 + 1 : rows - 1;
                int i2 = r0 + 2 < rows ? r0 + 2 : rows - 1;
                int L0 = __shfl(b2, r0, 64), H0 = __shfl(b2, 32 + r0, 64);
                int L1 = __shfl(b2, i1, 64), H1 = __shfl(b2, 32 + i1, 64);
                int L2 = __shfl(b2, i2, 64), H2 = __shfl(b2, 32 + i2, 64);
                int d0 = H0 - L0;
                int d1 = (r0 + 1 < rows) ? H1 - L1 : 0;
                int d2 = (r0 + 2 < rows) ? H2 - L2 : 0;
                stream3(rs, lane, L0, d0, L1, d1, L2, d2,
                        qx, qy, qz, sq, key);
            }
        }
        key = wave_min_u64(key);
    }

    if (lane == 0) {
        out[dir * N_PTS + origq]       = invord((unsigned)(key >> 32));
        out[(2 + dir) * N_PTS + origq] = (float)(unsigned)(key & 0xFFFFFFFFu);
    }
}

// ---- fallback (tiny workspace): brute-force direct kernel (proven r2) ----
__device__ __forceinline__ float np_pair(float sq, float sr,
                                         float qx, float qy, float qz,
                                         float rx, float ry, float rz) {
    float zz = __fadd_rn(__fadd_rn(__fmul_rn(qx, rx), __fmul_rn(qy, ry)),
                         __fmul_rn(qz, rz));
    return __fsub_rn(__fadd_rn(sq, sr), __fadd_rn(zz, zz));
}

__global__ __launch_bounds__(256) void chamfer_direct_kernel(
    const float* __restrict__ preds, const float* __restrict__ gts,
    float* __restrict__ out)
{
    __shared__ float4 spts[256];
    int bid = blockIdx.x;
    int dir = bid / QB79;
    int qb  = bid - dir * QB79;
    int q   = qb * 256 + threadIdx.x;

    const float* qpts = (dir == 0) ? preds : gts;
    const float* rpts = (dir == 0) ? gts   : preds;

    int qc = (q < N_PTS) ? q : (N_PTS - 1);
    float qx = qpts[qc*3+0], qy = qpts[qc*3+1], qz = qpts[qc*3+2];
    float sq = np_self_dot(qx, qy, qz);
    float best = 3.4e38f;
    int   bidx = 0;

    for (int t = 0; t < N_PTS; t += 256) {
        int cnt = min(256, N_PTS - t);
        __syncthreads();
        if ((int)threadIdx.x < cnt) {
            int j = t + threadIdx.x;
            float rx = rpts[j*3+0], ry = rpts[j*3+1], rz = rpts[j*3+2];
            spts[threadIdx.x] = make_float4(rx, ry, rz, np_self_dot(rx, ry, rz));
        }
        __syncthreads();
        for (int k = 0; k < cnt; ++k) {
            float4 r = spts[k];
            float d = np_pair(sq, r.w, qx, qy, qz, r.x, r.y, r.z);
            if (d < best) { best = d; bidx = t + k; }
        }
    }
    if (q < N_PTS) {
        out[dir * N_PTS + q]       = best;
        out[(2 + dir) * N_PTS + q] = (float)bidx;
    }
}

extern "C" void kernel_launch(void* const* d_in, const int* in_sizes, int n_in,
                              void* d_out, int out_size, void* d_ws, size_t ws_size,
                              hipStream_t stream) {
    const float* preds = (const float*)d_in[0];  // [20000, 3]
    const float* gts   = (const float*)d_in[1];  // [1, 20000, 3]
    float* out = (float*)d_out;

    char* w = (char*)d_ws;
    size_t sorted_b = (size_t)2 * N_PTS * sizeof(float4);   // 640000
    size_t bstart_b = (size_t)2 * (NC + 1) * sizeof(int);   // 131080
    size_t cursor_b = (size_t)2 * NC * sizeof(int);         // 131072
    size_t need = sorted_b + bstart_b + cursor_b;

    if (ws_size >= need) {
        float4* sorted = (float4*)w;
        int* bstart = (int*)(w + sorted_b);
        int* cursor = (int*)(w + sorted_b + bstart_b);

        hipMemsetAsync(cursor, 0, cursor_b, stream);
        k_hist<<<(2 * N_PTS + 255) / 256, 256, 0, stream>>>(preds, gts, cursor);
        k_scan<<<2, 1024, 0, stream>>>(cursor, bstart);
        k_scatter<<<(2 * N_PTS + 255) / 256, 256, 0, stream>>>(
            preds, gts, cursor, sorted);
        k_main<<<2 * N_PTS / 4, 256, 0, stream>>>(sorted, bstart, out);
    } else {
        chamfer_direct_kernel<<<2 * QB79, 256, 0, stream>>>(preds, gts, out);
    }
}